// Round 1
// baseline (142.631 us; speedup 1.0000x reference)
//
#include <hip/hip_runtime.h>

#define BB_ 8
#define VV_ 5023
#define FF_ 9976
#define HH_ 512

static constexpr long long OUT_UV   = 0;                                   // uvcoords_images (B,3,H,H)
static constexpr long long OUT_POS  = OUT_UV   + (long long)BB_*3*HH_*HH_; // pos_mask        (B,1,H,H)
static constexpr long long OUT_GRID = OUT_POS  + (long long)BB_*HH_*HH_;   // grid            (B,H,H,2)
static constexpr long long OUT_N    = OUT_GRID + (long long)BB_*HH_*HH_*2; // normals         (B,V,3)
static constexpr long long OUT_NIMG = OUT_N    + (long long)BB_*VV_*3;     // normal_images   (B,3,H,H)
static constexpr long long OUT_TN   = OUT_NIMG + (long long)BB_*3*HH_*HH_; // t_normals       (B,V,3)

__global__ void face_scatter(const float* __restrict__ verts,
                             const float* __restrict__ tverts,
                             const int*   __restrict__ faces,
                             float* __restrict__ accN,
                             float* __restrict__ accTN) {
    int idx = blockIdx.x * blockDim.x + threadIdx.x;
    if (idx >= BB_ * FF_) return;
    int b = idx / FF_;
    int f = idx - b * FF_;

    int i0 = faces[f * 3 + 0];
    int i1 = faces[f * 3 + 1];
    int i2 = faces[f * 3 + 2];

    {
        const float* vb = verts + (long long)b * VV_ * 3;
        float v0x = vb[i0*3+0], v0y = vb[i0*3+1], v0z = vb[i0*3+2];
        float v1x = vb[i1*3+0], v1y = vb[i1*3+1], v1z = vb[i1*3+2];
        float v2x = vb[i2*3+0], v2y = vb[i2*3+1], v2z = vb[i2*3+2];
        float ax = v1x - v0x, ay = v1y - v0y, az = v1z - v0z;
        float bx = v2x - v0x, by = v2y - v0y, bz = v2z - v0z;
        float nx = ay * bz - az * by;
        float ny = az * bx - ax * bz;
        float nz = ax * by - ay * bx;
        float* base = accN + (long long)b * VV_ * 3;
        atomicAdd(&base[i0*3+0], nx); atomicAdd(&base[i0*3+1], ny); atomicAdd(&base[i0*3+2], nz);
        atomicAdd(&base[i1*3+0], nx); atomicAdd(&base[i1*3+1], ny); atomicAdd(&base[i1*3+2], nz);
        atomicAdd(&base[i2*3+0], nx); atomicAdd(&base[i2*3+1], ny); atomicAdd(&base[i2*3+2], nz);
    }
    {
        const float* vb = tverts + (long long)b * VV_ * 3;
        float v0x = vb[i0*3+0], v0y = vb[i0*3+1], v0z = vb[i0*3+2] + 10.0f;
        float v1x = vb[i1*3+0], v1y = vb[i1*3+1], v1z = vb[i1*3+2] + 10.0f;
        float v2x = vb[i2*3+0], v2y = vb[i2*3+1], v2z = vb[i2*3+2] + 10.0f;
        float ax = v1x - v0x, ay = v1y - v0y, az = v1z - v0z;
        float bx = v2x - v0x, by = v2y - v0y, bz = v2z - v0z;
        float nx = ay * bz - az * by;
        float ny = az * bx - ax * bz;
        float nz = ax * by - ay * bx;
        float* base = accTN + (long long)b * VV_ * 3;
        atomicAdd(&base[i0*3+0], nx); atomicAdd(&base[i0*3+1], ny); atomicAdd(&base[i0*3+2], nz);
        atomicAdd(&base[i1*3+0], nx); atomicAdd(&base[i1*3+1], ny); atomicAdd(&base[i1*3+2], nz);
        atomicAdd(&base[i2*3+0], nx); atomicAdd(&base[i2*3+1], ny); atomicAdd(&base[i2*3+2], nz);
    }
}

__global__ void normalize_k(const float* __restrict__ accN,
                            const float* __restrict__ accTN,
                            float* __restrict__ outN,
                            float* __restrict__ outTN) {
    int idx = blockIdx.x * blockDim.x + threadIdx.x;
    if (idx >= BB_ * VV_) return;
    {
        float x = accN[idx*3+0], y = accN[idx*3+1], z = accN[idx*3+2];
        float inv = 1.0f / fmaxf(sqrtf(x*x + y*y + z*z), 1e-6f);
        outN[idx*3+0] = x * inv; outN[idx*3+1] = y * inv; outN[idx*3+2] = z * inv;
    }
    {
        float x = accTN[idx*3+0], y = accTN[idx*3+1], z = accTN[idx*3+2];
        float inv = 1.0f / fmaxf(sqrtf(x*x + y*y + z*z), 1e-6f);
        outTN[idx*3+0] = x * inv; outTN[idx*3+1] = y * inv; outTN[idx*3+2] = z * inv;
    }
}

__global__ void raster_k(const int*   __restrict__ p2f,
                         const float* __restrict__ bary,
                         const float* __restrict__ uvc,
                         const int*   __restrict__ faces,
                         const float* __restrict__ normals,
                         const float* __restrict__ tnormals,
                         float* __restrict__ out) {
    long long pix = (long long)blockIdx.x * blockDim.x + threadIdx.x;
    const long long NPIX = (long long)BB_ * HH_ * HH_;
    if (pix >= NPIX) return;
    int b  = (int)(pix / ((long long)HH_ * HH_));
    int yx = (int)(pix - (long long)b * HH_ * HH_);

    int pf = p2f[pix];
    float uv0 = 0.f, uv1 = 0.f, uv2 = 0.f;
    float n0 = 0.f, n1 = 0.f, n2 = 0.f;
    float pm = 0.f;

    if (pf >= 0) {
        int bb = pf / FF_;
        int ff = pf - bb * FF_;
        float w0 = bary[pix*3+0], w1 = bary[pix*3+1], w2 = bary[pix*3+2];

        int ia = faces[ff*3+0], ib = faces[ff*3+1], ic = faces[ff*3+2];

        const float* u = uvc + (long long)ff * 9;
        uv0 = w0*(u[0]*0.5f+0.5f) + w1*(u[3]*0.5f+0.5f) + w2*(u[6]*0.5f+0.5f);
        uv1 = w0*(u[1]*0.5f+0.5f) + w1*(u[4]*0.5f+0.5f) + w2*(u[7]*0.5f+0.5f);
        uv2 = w0*(u[2]*0.5f+0.5f) + w1*(u[5]*0.5f+0.5f) + w2*(u[8]*0.5f+0.5f);

        const float* nb = normals + (long long)bb * VV_ * 3;
        n0 = w0*nb[ia*3+0] + w1*nb[ib*3+0] + w2*nb[ic*3+0];
        n1 = w0*nb[ia*3+1] + w1*nb[ib*3+1] + w2*nb[ic*3+1];
        n2 = w0*nb[ia*3+2] + w1*nb[ib*3+2] + w2*nb[ic*3+2];

        const float* tb = tnormals + (long long)bb * VV_ * 3;
        float tnz = w0*tb[ia*3+2] + w1*tb[ib*3+2] + w2*tb[ic*3+2];
        pm = (tnz < -0.05f) ? 1.0f : 0.0f;
    }

    const long long HW = (long long)HH_ * HH_;
    out[OUT_UV + ((long long)(b*3+0))*HW + yx] = uv0;
    out[OUT_UV + ((long long)(b*3+1))*HW + yx] = uv1;
    out[OUT_UV + ((long long)(b*3+2))*HW + yx] = uv2;
    out[OUT_POS + (long long)b*HW + yx] = pm;
    out[OUT_GRID + ((long long)b*HW + yx)*2 + 0] = uv0;
    out[OUT_GRID + ((long long)b*HW + yx)*2 + 1] = uv1;
    out[OUT_NIMG + ((long long)(b*3+0))*HW + yx] = n0;
    out[OUT_NIMG + ((long long)(b*3+1))*HW + yx] = n1;
    out[OUT_NIMG + ((long long)(b*3+2))*HW + yx] = n2;
}

extern "C" void kernel_launch(void* const* d_in, const int* in_sizes, int n_in,
                              void* d_out, int out_size, void* d_ws, size_t ws_size,
                              hipStream_t stream) {
    const float* vertices  = (const float*)d_in[0];
    const float* tvertices = (const float*)d_in[1];
    const float* face_uvc  = (const float*)d_in[3];
    const float* bary      = (const float*)d_in[4];
    const int*   faces     = (const int*)d_in[5];
    const int*   p2f       = (const int*)d_in[6];

    float* out = (float*)d_out;
    float* accN  = (float*)d_ws;
    float* accTN = accN + (long long)BB_ * VV_ * 3;

    hipMemsetAsync(d_ws, 0, (size_t)2 * BB_ * VV_ * 3 * sizeof(float), stream);

    {
        int n = BB_ * FF_;
        face_scatter<<<(n + 255) / 256, 256, 0, stream>>>(vertices, tvertices, faces, accN, accTN);
    }
    {
        int n = BB_ * VV_;
        normalize_k<<<(n + 255) / 256, 256, 0, stream>>>(accN, accTN, out + OUT_N, out + OUT_TN);
    }
    {
        long long n = (long long)BB_ * HH_ * HH_;
        raster_k<<<(int)((n + 255) / 256), 256, 0, stream>>>(p2f, bary, face_uvc, faces,
                                                             out + OUT_N, out + OUT_TN, out);
    }
}

// Round 2
// 84.681 us; speedup vs baseline: 1.6843x; 1.6843x over previous
//
#include <hip/hip_runtime.h>

#define BB_ 8
#define VV_ 5023
#define FF_ 9976
#define HH_ 512

static constexpr long long OUT_UV   = 0;                                   // uvcoords_images (B,3,H,H)
static constexpr long long OUT_POS  = OUT_UV   + (long long)BB_*3*HH_*HH_; // pos_mask        (B,1,H,H)
static constexpr long long OUT_GRID = OUT_POS  + (long long)BB_*HH_*HH_;   // grid            (B,H,H,2)
static constexpr long long OUT_N    = OUT_GRID + (long long)BB_*HH_*HH_*2; // normals         (B,V,3)
static constexpr long long OUT_NIMG = OUT_N    + (long long)BB_*VV_*3;     // normal_images   (B,3,H,H)
static constexpr long long OUT_TN   = OUT_NIMG + (long long)BB_*3*HH_*HH_; // t_normals       (B,V,3)

// ---------------------------------------------------------------------------
// Kernel 1: per-(batch, mesh, chunk) block. Accumulate face normals into a
// 60 KB LDS accumulator with LDS atomics, then dump a dense partial to ws.
// All three reference scatter-adds equal cross(v1-v0, v2-v0) per face.
// ---------------------------------------------------------------------------
__global__ __launch_bounds__(256) void face_acc(const float* __restrict__ verts,
                                                const float* __restrict__ tverts,
                                                const int*   __restrict__ faces,
                                                float* __restrict__ partials,
                                                int C, int chunk) {
    __shared__ float acc[VV_ * 3];
    int blk = blockIdx.x;          // ((b*2 + m)*C + c)
    int c  = blk % C;
    int bm = blk / C;
    int m  = bm & 1;
    int b  = bm >> 1;

    for (int i = threadIdx.x; i < VV_ * 3; i += blockDim.x) acc[i] = 0.0f;
    __syncthreads();

    const float* vb = (m ? tverts : verts) + (long long)b * VV_ * 3;
    const float zoff = m ? 10.0f : 0.0f;

    int f0 = c * chunk;
    int f1 = min(f0 + chunk, FF_);
    for (int f = f0 + (int)threadIdx.x; f < f1; f += blockDim.x) {
        int i0 = faces[f * 3 + 0];
        int i1 = faces[f * 3 + 1];
        int i2 = faces[f * 3 + 2];
        float v0x = vb[i0*3+0], v0y = vb[i0*3+1], v0z = vb[i0*3+2] + zoff;
        float v1x = vb[i1*3+0], v1y = vb[i1*3+1], v1z = vb[i1*3+2] + zoff;
        float v2x = vb[i2*3+0], v2y = vb[i2*3+1], v2z = vb[i2*3+2] + zoff;
        float ax = v1x - v0x, ay = v1y - v0y, az = v1z - v0z;
        float bx = v2x - v0x, by = v2y - v0y, bz = v2z - v0z;
        float nx = ay * bz - az * by;
        float ny = az * bx - ax * bz;
        float nz = ax * by - ay * bx;
        atomicAdd(&acc[i0*3+0], nx); atomicAdd(&acc[i0*3+1], ny); atomicAdd(&acc[i0*3+2], nz);
        atomicAdd(&acc[i1*3+0], nx); atomicAdd(&acc[i1*3+1], ny); atomicAdd(&acc[i1*3+2], nz);
        atomicAdd(&acc[i2*3+0], nx); atomicAdd(&acc[i2*3+1], ny); atomicAdd(&acc[i2*3+2], nz);
    }
    __syncthreads();

    float* pout = partials + (long long)blk * VV_ * 3;
    for (int i = threadIdx.x; i < VV_ * 3; i += blockDim.x) pout[i] = acc[i];
}

// ---------------------------------------------------------------------------
// Kernel 2: merge C partials per (b, mesh, vertex), normalize, write outputs.
// Fully coalesced reads/writes.
// ---------------------------------------------------------------------------
__global__ void merge_norm(const float* __restrict__ partials, int C,
                           float* __restrict__ outN, float* __restrict__ outTN) {
    int idx = blockIdx.x * blockDim.x + threadIdx.x;   // over B*V
    if (idx >= BB_ * VV_) return;
    int b = idx / VV_;
    int v = idx - b * VV_;
    #pragma unroll
    for (int m = 0; m < 2; ++m) {
        float x = 0.f, y = 0.f, z = 0.f;
        for (int c = 0; c < C; ++c) {
            const float* p = partials + ((long long)((b*2 + m)*C + c)) * VV_ * 3 + (long long)v * 3;
            x += p[0]; y += p[1]; z += p[2];
        }
        float inv = 1.0f / fmaxf(sqrtf(x*x + y*y + z*z), 1e-6f);
        float* o = (m ? outTN : outN) + (long long)idx * 3;
        o[0] = x * inv; o[1] = y * inv; o[2] = z * inv;
    }
}

// ---------------------------------------------------------------------------
// Kernel 3: build one 96 B record per (b,f) containing everything raster
// needs: pre-scaled uv (9), vertex normals (9), t-normal z (3), pad (3).
// ---------------------------------------------------------------------------
__global__ void build_rec(const int*   __restrict__ faces,
                          const float* __restrict__ uvc,
                          const float* __restrict__ outN,
                          const float* __restrict__ outTN,
                          float* __restrict__ recs) {
    int t = blockIdx.x * blockDim.x + threadIdx.x;
    if (t >= BB_ * FF_) return;
    int b = t / FF_;
    int f = t - b * FF_;
    int ia = faces[f*3+0], ib = faces[f*3+1], ic = faces[f*3+2];

    const float* u = uvc + (long long)f * 9;
    float r0 = u[0]*0.5f+0.5f, r1 = u[1]*0.5f+0.5f, r2 = u[2]*0.5f+0.5f;
    float r3 = u[3]*0.5f+0.5f, r4 = u[4]*0.5f+0.5f, r5 = u[5]*0.5f+0.5f;
    float r6 = u[6]*0.5f+0.5f, r7 = u[7]*0.5f+0.5f, r8 = u[8]*0.5f+0.5f;

    const float* nb = outN + (long long)b * VV_ * 3;
    float r9  = nb[ia*3+0], r10 = nb[ia*3+1], r11 = nb[ia*3+2];
    float r12 = nb[ib*3+0], r13 = nb[ib*3+1], r14 = nb[ib*3+2];
    float r15 = nb[ic*3+0], r16 = nb[ic*3+1], r17 = nb[ic*3+2];

    const float* tb = outTN + (long long)b * VV_ * 3;
    float r18 = tb[ia*3+2], r19 = tb[ib*3+2], r20 = tb[ic*3+2];

    float4* o = (float4*)(recs + (long long)t * 24);
    o[0] = make_float4(r0,  r1,  r2,  r3);
    o[1] = make_float4(r4,  r5,  r6,  r7);
    o[2] = make_float4(r8,  r9,  r10, r11);
    o[3] = make_float4(r12, r13, r14, r15);
    o[4] = make_float4(r16, r17, r18, r19);
    o[5] = make_float4(r20, 0.f, 0.f, 0.f);
}

// ---------------------------------------------------------------------------
// Kernel 4: raster. Per hit pixel: 6 float4 loads from one contiguous record
// (exactly 2 cache lines) + coalesced p2f/bary streams + coalesced writes.
// ---------------------------------------------------------------------------
__global__ __launch_bounds__(256) void raster2(const int*   __restrict__ p2f,
                                               const float* __restrict__ bary,
                                               const float* __restrict__ recs,
                                               float* __restrict__ out) {
    int pix = blockIdx.x * blockDim.x + threadIdx.x;
    const int NPIX = BB_ * HH_ * HH_;
    if (pix >= NPIX) return;
    int b  = pix >> 18;          // HH*HH = 262144 = 2^18
    int yx = pix & (HH_*HH_ - 1);

    int pf = p2f[pix];
    float uv0 = 0.f, uv1 = 0.f, uv2 = 0.f;
    float n0 = 0.f, n1 = 0.f, n2 = 0.f;
    float pm = 0.f;

    if (pf >= 0) {
        float w0 = bary[pix*3+0], w1 = bary[pix*3+1], w2 = bary[pix*3+2];
        const float4* R = (const float4*)(recs + (long long)pf * 24);
        float4 q0 = R[0], q1 = R[1], q2 = R[2], q3 = R[3], q4 = R[4], q5 = R[5];
        uv0 = w0*q0.x + w1*q0.w + w2*q1.z;
        uv1 = w0*q0.y + w1*q1.x + w2*q1.w;
        uv2 = w0*q0.z + w1*q1.y + w2*q2.x;
        n0  = w0*q2.y + w1*q3.x + w2*q3.w;
        n1  = w0*q2.z + w1*q3.y + w2*q4.x;
        n2  = w0*q2.w + w1*q3.z + w2*q4.y;
        float tnz = w0*q4.z + w1*q4.w + w2*q5.x;
        pm = (tnz < -0.05f) ? 1.0f : 0.0f;
    }

    const long long HW = (long long)HH_ * HH_;
    out[OUT_UV + ((long long)(b*3+0))*HW + yx] = uv0;
    out[OUT_UV + ((long long)(b*3+1))*HW + yx] = uv1;
    out[OUT_UV + ((long long)(b*3+2))*HW + yx] = uv2;
    out[OUT_POS + (long long)b*HW + yx] = pm;
    ((float2*)(out + OUT_GRID))[(long long)b*HW + yx] = make_float2(uv0, uv1);
    out[OUT_NIMG + ((long long)(b*3+0))*HW + yx] = n0;
    out[OUT_NIMG + ((long long)(b*3+1))*HW + yx] = n1;
    out[OUT_NIMG + ((long long)(b*3+2))*HW + yx] = n2;
}

extern "C" void kernel_launch(void* const* d_in, const int* in_sizes, int n_in,
                              void* d_out, int out_size, void* d_ws, size_t ws_size,
                              hipStream_t stream) {
    const float* vertices  = (const float*)d_in[0];
    const float* tvertices = (const float*)d_in[1];
    const float* face_uvc  = (const float*)d_in[3];
    const float* bary      = (const float*)d_in[4];
    const int*   faces     = (const int*)d_in[5];
    const int*   p2f       = (const int*)d_in[6];

    float* out = (float*)d_out;

    // ws layout: [records: B*F*24 floats][partials: B*2*C*V*3 floats]
    const size_t REC_FLOATS = (size_t)BB_ * FF_ * 24;
    const size_t REC_BYTES  = REC_FLOATS * sizeof(float);
    const size_t PARTIAL_ONE = (size_t)BB_ * 2 * VV_ * 3 * sizeof(float); // per C
    int C = 8;
    while (C > 1 && REC_BYTES + (size_t)C * PARTIAL_ONE > ws_size) C >>= 1;

    float* recs     = (float*)d_ws;
    float* partials = recs + REC_FLOATS;

    int chunk = (FF_ + C - 1) / C;

    face_acc<<<BB_ * 2 * C, 256, 0, stream>>>(vertices, tvertices, faces, partials, C, chunk);

    {
        int n = BB_ * VV_;
        merge_norm<<<(n + 255) / 256, 256, 0, stream>>>(partials, C, out + OUT_N, out + OUT_TN);
    }
    {
        int n = BB_ * FF_;
        build_rec<<<(n + 255) / 256, 256, 0, stream>>>(faces, face_uvc, out + OUT_N, out + OUT_TN, recs);
    }
    {
        int n = BB_ * HH_ * HH_;
        raster2<<<(n + 255) / 256, 256, 0, stream>>>(p2f, bary, recs, out);
    }
}